// Round 1
// baseline (692.052 us; speedup 1.0000x reference)
//
#include <hip/hip_runtime.h>
#include <hip/hip_fp16.h>

#define IN_F   100000
#define OUT_F  100000
#define NNZ_N  1600000
#define TC     256
#define TBLK   ((IN_F + TC - 1) / TC)      // 391 transpose blocks
#define SBLK   ((NNZ_N + 255) / 256)       // 6250 scan blocks
#define RBLK   ((OUT_F + 63) / 64)         // 1563 row blocks
#define NCH    4
#define CHW    25000                        // col chunk width: 25000*128B = 3.2 MB < 4 MB/XCD L2

__device__ __forceinline__ float2 h2f(unsigned u) {
    const __half2 h = *reinterpret_cast<const __half2*>(&u);
    return __half22float2(h);
}

// ---------------------------------------------------------------------------
// Prep: blocks [0,TBLK) transpose x (64,IN) f32 -> xh (IN,64) f16
// (u32 index: col*32 + pair, pair p = batches 2p,2p+1). Blocks [TBLK,TBLK+SBLK)
// do the rowstart linear scan over sorted rows.
// ---------------------------------------------------------------------------
__global__ __launch_bounds__(256) void k_prep(
    const float* __restrict__ x,
    const int*   __restrict__ rows,
    unsigned* __restrict__ xh,
    int*      __restrict__ rstart) {
    __shared__ unsigned tile[TC][33];
    const int bid = blockIdx.x;
    const int t   = threadIdx.x;

    if (bid < TBLK) {
        const int i0   = bid * TC;
        const int colr = i0 + t;
        if (colr < IN_F) {
            #pragma unroll 8
            for (int p = 0; p < 32; ++p) {
                const float a = x[(size_t)(2 * p)     * IN_F + colr];
                const float b = x[(size_t)(2 * p + 1) * IN_F + colr];
                const __half2 h = __floats2half2_rn(a, b);
                tile[t][p] = *reinterpret_cast<const unsigned*>(&h);
            }
        }
        __syncthreads();
        const int u  = t & 31;              // batch pair
        const int c8 = t >> 5;
        for (int cc = c8; cc < TC; cc += 8) {
            const int col = i0 + cc;
            if (col < IN_F)
                xh[(size_t)col * 32 + u] = tile[cc][u];
        }
    } else {
        const int e = (bid - TBLK) * 256 + t;
        if (e >= NNZ_N) return;
        const int cur  = rows[e];
        const int prev = (e == 0) ? -1 : rows[e - 1];
        for (int r = prev + 1; r <= cur; ++r) rstart[r] = e;
        if (e == NNZ_N - 1)
            for (int r = cur + 1; r <= OUT_F; ++r) rstart[r] = NNZ_N;
    }
}

// ---------------------------------------------------------------------------
// Bucket: one block per 64-row output block. Partitions the block's edge
// segment [rstart[r0], rstart[r0+64]) into NCH col-chunks (order within a
// chunk irrelevant: accumulation is commutative). Packs (col | lrow<<17, val)
// and records the 5 chunk boundaries in cbs[b*5+0..4].
// ---------------------------------------------------------------------------
__global__ __launch_bounds__(256) void k_bucket(
    const int*   __restrict__ rows,
    const int*   __restrict__ cols,
    const float* __restrict__ vals,
    const int*   __restrict__ rstart,
    uint2* __restrict__ pairs,
    int*   __restrict__ cbs) {
    __shared__ int cnt[NCH];
    __shared__ int off[NCH];
    const int b  = blockIdx.x;
    const int t  = threadIdx.x;
    const int r0 = b * 64;
    const int re = (r0 + 64 < OUT_F) ? r0 + 64 : OUT_F;
    const int s  = rstart[r0];
    const int e  = rstart[re];

    if (t < NCH) cnt[t] = 0;
    __syncthreads();
    for (int i = s + t; i < e; i += 256)
        atomicAdd(&cnt[cols[i] / CHW], 1);
    __syncthreads();
    if (t == 0) {
        int acc = s;
        #pragma unroll
        for (int k = 0; k < NCH; ++k) {
            cbs[b * 5 + k] = acc;
            off[k] = acc;
            acc += cnt[k];
        }
        cbs[b * 5 + NCH] = acc;            // == e
    }
    __syncthreads();
    for (int i = s + t; i < e; i += 256) {
        const int c  = cols[i];
        const int k  = c / CHW;
        const int lr = rows[i] - r0;
        const int pos = atomicAdd(&off[k], 1);
        pairs[pos] = make_uint2((unsigned)c | ((unsigned)lr << 17),
                                __float_as_uint(vals[i]));
    }
}

// ---------------------------------------------------------------------------
// SpMM: block = 512 threads = 64 groups of 8 lanes. Edge-parallel: group g
// consumes edges s+g, s+g+64, ... of the current chunk segment (perfect
// balance, no per-row divergence). Lane sub in [0,8) loads uint4 = 8 halves
// = batches 8sub..8sub+7 and accumulates into the LDS tile via ds_add_f32.
// Chunk phases keep the live xh slice (3.2 MB) resident in each XCD's L2.
// ---------------------------------------------------------------------------
__global__ __launch_bounds__(512, 4) void k_spmm(
    const uint4* __restrict__ xh4,        // col*8 + sub
    const uint2* __restrict__ pairs,
    const int*   __restrict__ cbs,
    const float* __restrict__ bias,
    float* __restrict__ out) {
    __shared__ float tile[64][65];
    const int b    = blockIdx.x;
    const int t    = threadIdx.x;
    const int lane = t & 63;
    const int w    = t >> 6;              // wave 0..7
    const int g    = t >> 3;              // group 0..63
    const int sub  = t & 7;               // batch octet

    float* tp = &tile[0][0];
    for (int i = t; i < 64 * 65; i += 512) tp[i] = 0.f;
    __syncthreads();

    #pragma unroll
    for (int k = 0; k < NCH; ++k) {
        const int s = cbs[b * 5 + k];
        const int e = cbs[b * 5 + k + 1];
        for (int i = s + g; i < e; i += 64) {
            const uint2 p = pairs[i];
            const float v = __uint_as_float(p.y);
            const int col = p.x & 0x1FFFF;
            const int lr  = (int)(p.x >> 17);
            const uint4 u = xh4[(size_t)col * 8 + sub];
            float* row = &tile[lr][sub << 3];
            float2 f;
            f = h2f(u.x); unsafeAtomicAdd(row + 0, v * f.x); unsafeAtomicAdd(row + 1, v * f.y);
            f = h2f(u.y); unsafeAtomicAdd(row + 2, v * f.x); unsafeAtomicAdd(row + 3, v * f.y);
            f = h2f(u.z); unsafeAtomicAdd(row + 4, v * f.x); unsafeAtomicAdd(row + 5, v * f.y);
            f = h2f(u.w); unsafeAtomicAdd(row + 6, v * f.x); unsafeAtomicAdd(row + 7, v * f.y);
        }
        __syncthreads();                  // phase-align chunks across the block
    }

    const int rc = b * 64 + lane;
    if (rc < OUT_F) {
        const float bv = bias[rc];
        for (int bb = w; bb < 64; bb += 8)
            out[(size_t)bb * OUT_F + rc] = tile[lane][bb] + bv;
    }
}

// ---------------------------------------------------------------------------
// Fallback (insufficient ws): gather from native x layout. Correct, slow.
// ---------------------------------------------------------------------------
__global__ __launch_bounds__(256) void k_spmm_fallback(
    const float* __restrict__ x,
    const float* __restrict__ vals,
    const int*   __restrict__ rows,
    const int*   __restrict__ cols,
    const float* __restrict__ bias,
    float* __restrict__ out) {
    __shared__ int   rstart[65];
    __shared__ float tile[64][65];
    const int r0   = blockIdx.x * 64;
    const int t    = threadIdx.x;
    const int lane = t & 63;
    const int w    = t >> 6;
    if (t < 65) {
        const int target = r0 + t;
        int lo = 0, hi = NNZ_N;
        while (lo < hi) {
            const int mid = (lo + hi) >> 1;
            if (rows[mid] < target) lo = mid + 1; else hi = mid;
        }
        rstart[t] = lo;
    }
    __syncthreads();
    for (int j = w; j < 64; j += 4) {
        const int s = rstart[j], e = rstart[j + 1];
        float acc = 0.f;
        const size_t base = (size_t)lane * IN_F;
        for (int idx = s; idx < e; ++idx)
            acc = fmaf(vals[idx], x[base + cols[idx]], acc);
        tile[j][lane] = acc;
    }
    __syncthreads();
    const int c = lane;
    if (r0 + c < OUT_F) {
        const float bv = bias[r0 + c];
        for (int bb = w; bb < 64; bb += 4)
            out[(size_t)bb * OUT_F + (r0 + c)] = tile[c][bb] + bv;
    }
}

extern "C" void kernel_launch(void* const* d_in, const int* in_sizes, int n_in,
                              void* d_out, int out_size, void* d_ws, size_t ws_size,
                              hipStream_t stream) {
    const float* x      = (const float*)d_in[0];
    const float* values = (const float*)d_in[1];
    const float* bias   = (const float*)d_in[2];
    const int*   rows   = (const int*)d_in[3];
    const int*   cols   = (const int*)d_in[4];
    float*       out    = (float*)d_out;

    const size_t xh_bytes = (size_t)IN_F * 32 * sizeof(unsigned);   // 12.8 MB
    const size_t rs_off   = (xh_bytes + 255) & ~(size_t)255;
    const size_t rs_bytes = (size_t)(OUT_F + 1) * sizeof(int);
    const size_t pr_off   = (rs_off + rs_bytes + 255) & ~(size_t)255;
    const size_t pr_bytes = (size_t)NNZ_N * sizeof(uint2);
    const size_t cb_off   = (pr_off + pr_bytes + 255) & ~(size_t)255;
    const size_t need     = cb_off + (size_t)RBLK * 5 * sizeof(int); // ~26.5 MB

    if (ws_size >= need) {
        unsigned* xh     = (unsigned*)d_ws;
        int*      rstart = (int*)((char*)d_ws + rs_off);
        uint2*    pairs  = (uint2*)((char*)d_ws + pr_off);
        int*      cbs    = (int*)((char*)d_ws + cb_off);
        k_prep<<<TBLK + SBLK, 256, 0, stream>>>(x, rows, xh, rstart);
        k_bucket<<<RBLK, 256, 0, stream>>>(rows, cols, values, rstart, pairs, cbs);
        k_spmm<<<RBLK, 512, 0, stream>>>((const uint4*)xh, pairs, cbs, bias, out);
    } else {
        k_spmm_fallback<<<RBLK, 256, 0, stream>>>(x, values, rows, cols, bias, out);
    }
}

// Round 2
// 149.125 us; speedup vs baseline: 4.6407x; 4.6407x over previous
//
#include <hip/hip_runtime.h>
#include <hip/hip_fp16.h>

#define IN_F   100000
#define OUT_F  100000
#define NNZ_N  1600000
#define TC     256
#define TBLK   ((IN_F + TC - 1) / TC)      // 391 transpose blocks
#define RBLK   ((OUT_F + 63) / 64)         // 1563 row blocks
#define NCH    4
#define CHW    25000                        // col chunk: 25000*128B = 3.2 MB < 4 MB/XCD L2

__device__ __forceinline__ float2 h2f(unsigned u) {
    const __half2 h = *reinterpret_cast<const __half2*>(&u);
    return __half22float2(h);
}

// ---------------------------------------------------------------------------
// Fused prep. Blocks [0,TBLK): transpose x (64,IN) f32 -> xh (IN,64) f16
// (u32 index: col*32 + pair, pair p = batches 2p,2p+1).
// Blocks [TBLK, TBLK+RBLK): per 64-row output block, sort the block's edge
// segment into 256 bins keyed by (chunk, local_row) via LDS histogram +
// wave scan + scatter. Emits pairs (col,val) in bin order and the 257 bin
// boundaries cs[b*257 + 0..256]. Row-owning groups in k_spmm then read
// contiguous per-(chunk,row) segments -> register accumulation, and chunk
// phases keep the live 3.2 MB xh slice L2-resident.
// ---------------------------------------------------------------------------
__global__ __launch_bounds__(256) void k_prep(
    const float* __restrict__ x,
    const int*   __restrict__ rows,
    const int*   __restrict__ cols,
    const float* __restrict__ vals,
    unsigned* __restrict__ xh,
    uint2*    __restrict__ pairs,
    int*      __restrict__ cs) {
    __shared__ unsigned tile[TC][33];
    __shared__ int hist[256];
    __shared__ int off[256];
    __shared__ int sb[2];
    const int bid = blockIdx.x;
    const int t   = threadIdx.x;

    if (bid < TBLK) {
        const int i0   = bid * TC;
        const int colr = i0 + t;
        if (colr < IN_F) {
            #pragma unroll 8
            for (int p = 0; p < 32; ++p) {
                const float a = x[(size_t)(2 * p)     * IN_F + colr];
                const float b = x[(size_t)(2 * p + 1) * IN_F + colr];
                const __half2 h = __floats2half2_rn(a, b);
                tile[t][p] = *reinterpret_cast<const unsigned*>(&h);
            }
        }
        __syncthreads();
        const int u  = t & 31;              // batch pair
        const int c8 = t >> 5;
        for (int cc = c8; cc < TC; cc += 8) {
            const int col = i0 + cc;
            if (col < IN_F)
                xh[(size_t)col * 32 + u] = tile[cc][u];
        }
    } else {
        const int b  = bid - TBLK;
        const int r0 = b * 64;
        // find this block's edge segment (rows sorted)
        if (t < 2) {
            const int target = r0 + t * 64;
            int lo = 0, hi = NNZ_N;
            while (lo < hi) {
                const int mid = (lo + hi) >> 1;
                if (rows[mid] < target) lo = mid + 1; else hi = mid;
            }
            sb[t] = lo;
        }
        hist[t] = 0;
        __syncthreads();
        const int s = sb[0], e = sb[1];
        for (int i = s + t; i < e; i += 256)
            atomicAdd(&hist[(cols[i] / CHW) * 64 + (rows[i] - r0)], 1);
        __syncthreads();
        // exclusive scan of 256 bins by wave 0 (4 bins/lane + lane scan)
        if (t < 64) {
            const int s0 = hist[4 * t + 0];
            const int s1 = hist[4 * t + 1];
            const int s2 = hist[4 * t + 2];
            const int s3 = hist[4 * t + 3];
            const int tot = s0 + s1 + s2 + s3;
            int sc = tot;
            #pragma unroll
            for (int d = 1; d < 64; d <<= 1) {
                const int n = __shfl_up(sc, d);
                if (t >= d) sc += n;
            }
            int base = s + (sc - tot);       // exclusive prefix
            off[4 * t + 0] = base; cs[(size_t)b * 257 + 4 * t + 0] = base; base += s0;
            off[4 * t + 1] = base; cs[(size_t)b * 257 + 4 * t + 1] = base; base += s1;
            off[4 * t + 2] = base; cs[(size_t)b * 257 + 4 * t + 2] = base; base += s2;
            off[4 * t + 3] = base; cs[(size_t)b * 257 + 4 * t + 3] = base; base += s3;
        }
        if (t == 0) cs[(size_t)b * 257 + 256] = e;
        __syncthreads();
        for (int i = s + t; i < e; i += 256) {
            const int c   = cols[i];
            const int bin = (c / CHW) * 64 + (rows[i] - r0);
            const int pos = atomicAdd(&off[bin], 1);
            pairs[pos] = make_uint2((unsigned)c, __float_as_uint(vals[i]));
        }
    }
}

// ---------------------------------------------------------------------------
// SpMM: block = 512 threads = 64 groups of 8 lanes. Group g owns row r0+g;
// lane sub in [0,8) loads uint4 = 8 halves = batches 8sub..8sub+7.
// Per chunk k, group g reads its contiguous bin [rs[k*64+g], rs[k*64+g+1])
// with the unroll-4 pipeline (8 independent cache lines in flight per group,
// 32 per wave). fp32 register accumulate across chunks; barrier per chunk
// keeps resident blocks phase-aligned so the xh slice stays in L2.
// ---------------------------------------------------------------------------
__global__ __launch_bounds__(512, 4) void k_spmm(
    const uint4* __restrict__ xh4,        // col*8 + sub
    const uint2* __restrict__ pairs,
    const int*   __restrict__ cs,
    const float* __restrict__ bias,
    float* __restrict__ out) {
    __shared__ int   rs[257];
    __shared__ float tile[64][65];
    const int b    = blockIdx.x;
    const int t    = threadIdx.x;
    const int lane = t & 63;
    const int w    = t >> 6;              // wave 0..7
    const int g    = t >> 3;              // group -> local row 0..63
    const int sub  = t & 7;               // batch octet

    if (t < 257) rs[t] = cs[(size_t)b * 257 + t];
    __syncthreads();

    float acc[8];
    #pragma unroll
    for (int i = 0; i < 8; ++i) acc[i] = 0.f;

    #pragma unroll
    for (int k = 0; k < NCH; ++k) {
        const int s = rs[k * 64 + g];
        const int e = rs[k * 64 + g + 1];   // bins contiguous; rs[256] = end
        for (int base = s; base < e; base += 4) {
            const int e1 = e - 1;
            const int i1 = (base + 1 < e) ? base + 1 : e1;
            const int i2 = (base + 2 < e) ? base + 2 : e1;
            const int i3 = (base + 3 < e) ? base + 3 : e1;
            const uint2 p0 = pairs[base];
            const uint2 p1 = pairs[i1];
            const uint2 p2 = pairs[i2];
            const uint2 p3 = pairs[i3];
            const float v0 = __uint_as_float(p0.y);
            const float v1 = (base + 1 < e) ? __uint_as_float(p1.y) : 0.f;
            const float v2 = (base + 2 < e) ? __uint_as_float(p2.y) : 0.f;
            const float v3 = (base + 3 < e) ? __uint_as_float(p3.y) : 0.f;
            const uint4 u0 = xh4[(size_t)p0.x * 8 + sub];
            const uint4 u1 = xh4[(size_t)p1.x * 8 + sub];
            const uint4 u2 = xh4[(size_t)p2.x * 8 + sub];
            const uint4 u3 = xh4[(size_t)p3.x * 8 + sub];
            float2 f;
            f = h2f(u0.x); acc[0] = fmaf(v0, f.x, acc[0]); acc[1] = fmaf(v0, f.y, acc[1]);
            f = h2f(u0.y); acc[2] = fmaf(v0, f.x, acc[2]); acc[3] = fmaf(v0, f.y, acc[3]);
            f = h2f(u0.z); acc[4] = fmaf(v0, f.x, acc[4]); acc[5] = fmaf(v0, f.y, acc[5]);
            f = h2f(u0.w); acc[6] = fmaf(v0, f.x, acc[6]); acc[7] = fmaf(v0, f.y, acc[7]);
            f = h2f(u1.x); acc[0] = fmaf(v1, f.x, acc[0]); acc[1] = fmaf(v1, f.y, acc[1]);
            f = h2f(u1.y); acc[2] = fmaf(v1, f.x, acc[2]); acc[3] = fmaf(v1, f.y, acc[3]);
            f = h2f(u1.z); acc[4] = fmaf(v1, f.x, acc[4]); acc[5] = fmaf(v1, f.y, acc[5]);
            f = h2f(u1.w); acc[6] = fmaf(v1, f.x, acc[6]); acc[7] = fmaf(v1, f.y, acc[7]);
            f = h2f(u2.x); acc[0] = fmaf(v2, f.x, acc[0]); acc[1] = fmaf(v2, f.y, acc[1]);
            f = h2f(u2.y); acc[2] = fmaf(v2, f.x, acc[2]); acc[3] = fmaf(v2, f.y, acc[3]);
            f = h2f(u2.z); acc[4] = fmaf(v2, f.x, acc[4]); acc[5] = fmaf(v2, f.y, acc[5]);
            f = h2f(u2.w); acc[6] = fmaf(v2, f.x, acc[6]); acc[7] = fmaf(v2, f.y, acc[7]);
            f = h2f(u3.x); acc[0] = fmaf(v3, f.x, acc[0]); acc[1] = fmaf(v3, f.y, acc[1]);
            f = h2f(u3.y); acc[2] = fmaf(v3, f.x, acc[2]); acc[3] = fmaf(v3, f.y, acc[3]);
            f = h2f(u3.z); acc[4] = fmaf(v3, f.x, acc[4]); acc[5] = fmaf(v3, f.y, acc[5]);
            f = h2f(u3.w); acc[6] = fmaf(v3, f.x, acc[6]); acc[7] = fmaf(v3, f.y, acc[7]);
        }
        __syncthreads();                  // phase-align chunks across the block
    }

    // tile[g][8sub+i]: bank = (g + 8sub + i) mod 32 -> 2 lanes/bank = free
    #pragma unroll
    for (int i = 0; i < 8; ++i) tile[g][(sub << 3) + i] = acc[i];
    __syncthreads();

    const int rc = b * 64 + lane;
    if (rc < OUT_F) {
        const float bv = bias[rc];
        for (int bb = w; bb < 64; bb += 8)
            out[(size_t)bb * OUT_F + rc] = tile[lane][bb] + bv;
    }
}

// ---------------------------------------------------------------------------
// Fallback (insufficient ws): gather from native x layout. Correct, slow.
// ---------------------------------------------------------------------------
__global__ __launch_bounds__(256) void k_spmm_fallback(
    const float* __restrict__ x,
    const float* __restrict__ vals,
    const int*   __restrict__ rows,
    const int*   __restrict__ cols,
    const float* __restrict__ bias,
    float* __restrict__ out) {
    __shared__ int   rstart[65];
    __shared__ float tile[64][65];
    const int r0   = blockIdx.x * 64;
    const int t    = threadIdx.x;
    const int lane = t & 63;
    const int w    = t >> 6;
    if (t < 65) {
        const int target = r0 + t;
        int lo = 0, hi = NNZ_N;
        while (lo < hi) {
            const int mid = (lo + hi) >> 1;
            if (rows[mid] < target) lo = mid + 1; else hi = mid;
        }
        rstart[t] = lo;
    }
    __syncthreads();
    for (int j = w; j < 64; j += 4) {
        const int s = rstart[j], e = rstart[j + 1];
        float acc = 0.f;
        const size_t base = (size_t)lane * IN_F;
        for (int idx = s; idx < e; ++idx)
            acc = fmaf(vals[idx], x[base + cols[idx]], acc);
        tile[j][lane] = acc;
    }
    __syncthreads();
    const int c = lane;
    if (r0 + c < OUT_F) {
        const float bv = bias[r0 + c];
        for (int bb = w; bb < 64; bb += 4)
            out[(size_t)bb * OUT_F + (r0 + c)] = tile[c][bb] + bv;
    }
}

extern "C" void kernel_launch(void* const* d_in, const int* in_sizes, int n_in,
                              void* d_out, int out_size, void* d_ws, size_t ws_size,
                              hipStream_t stream) {
    const float* x      = (const float*)d_in[0];
    const float* values = (const float*)d_in[1];
    const float* bias   = (const float*)d_in[2];
    const int*   rows   = (const int*)d_in[3];
    const int*   cols   = (const int*)d_in[4];
    float*       out    = (float*)d_out;

    const size_t xh_bytes = (size_t)IN_F * 32 * sizeof(unsigned);   // 12.8 MB
    const size_t pr_off   = (xh_bytes + 255) & ~(size_t)255;
    const size_t pr_bytes = (size_t)NNZ_N * sizeof(uint2);          // 12.8 MB
    const size_t cb_off   = (pr_off + pr_bytes + 255) & ~(size_t)255;
    const size_t need     = cb_off + (size_t)RBLK * 257 * sizeof(int); // ~27.3 MB

    if (ws_size >= need) {
        unsigned* xh    = (unsigned*)d_ws;
        uint2*    pairs = (uint2*)((char*)d_ws + pr_off);
        int*      cs    = (int*)((char*)d_ws + cb_off);
        k_prep<<<TBLK + RBLK, 256, 0, stream>>>(x, rows, cols, values, xh, pairs, cs);
        k_spmm<<<RBLK, 512, 0, stream>>>((const uint4*)xh, pairs, cs, bias, out);
    } else {
        k_spmm_fallback<<<RBLK, 256, 0, stream>>>(x, values, rows, cols, bias, out);
    }
}

// Round 4
// 136.240 us; speedup vs baseline: 5.0797x; 1.0946x over previous
//
#include <hip/hip_runtime.h>
#include <hip/hip_fp16.h>

#define IN_F   100000
#define OUT_F  100000
#define NNZ_N  1600000
#define TC     256
#define TBLK   ((IN_F + TC - 1) / TC)      // 391 transpose blocks
#define RBLK   ((OUT_F + 63) / 64)         // 1563 spmm blocks

__device__ __forceinline__ float2 h2f(unsigned u) {
    const __half2 h = *reinterpret_cast<const __half2*>(&u);
    return __half22float2(h);
}

// ---------------------------------------------------------------------------
// Transpose x (64,IN) f32 -> xh (IN,64) f16. u32 word index: col*32 + p,
// pair p = batches 2p,2p+1. LDS tile makes both sides coalesced.
// ---------------------------------------------------------------------------
__global__ __launch_bounds__(256) void k_transpose(
    const float* __restrict__ x,
    unsigned*    __restrict__ xh) {
    __shared__ unsigned tile[TC][33];
    const int i0   = blockIdx.x * TC;
    const int t    = threadIdx.x;
    const int colr = i0 + t;
    if (colr < IN_F) {
        #pragma unroll 8
        for (int p = 0; p < 32; ++p) {
            const float a = x[(size_t)(2 * p)     * IN_F + colr];
            const float b = x[(size_t)(2 * p + 1) * IN_F + colr];
            const __half2 h = __floats2half2_rn(a, b);
            tile[t][p] = *reinterpret_cast<const unsigned*>(&h);
        }
    }
    __syncthreads();
    const int u  = t & 31;                  // batch pair
    const int c8 = t >> 5;
    for (int cc = c8; cc < TC; cc += 8) {
        const int col = i0 + cc;
        if (col < IN_F)
            xh[(size_t)col * 32 + u] = tile[cc][u];
    }
}

// ---------------------------------------------------------------------------
// SpMM: block = 512 threads = 8 waves = 64 rows. Wave 0 binary-searches the
// 65 row boundaries from sorted rows (no separate scan kernel, no rstart
// round-trip). Each 8-lane group owns ONE row; lane sub in [0,8) loads
// uint4 = 8 halves = batches 8sub..8sub+7. Unroll-4 -> 32 independent gather
// lines in flight per wave. Edges read directly from cols/vals (no packed
// pairs intermediate). fp32 register accumulate; LDS transpose epilogue.
// ---------------------------------------------------------------------------
__global__ __launch_bounds__(512, 4) void k_spmm(
    const uint4* __restrict__ xh4,        // col*8 + sub
    const int*   __restrict__ rows,
    const int*   __restrict__ cols,
    const float* __restrict__ vals,
    const float* __restrict__ bias,
    float* __restrict__ out) {
    __shared__ int   rs[65];
    __shared__ float tile[64][65];
    const int r0   = blockIdx.x * 64;
    const int t    = threadIdx.x;
    const int lane = t & 63;
    const int w    = t >> 6;

    if (t < 65) {
        const int target = r0 + t;
        int lo = 0, hi = NNZ_N;
        while (lo < hi) {
            const int mid = (lo + hi) >> 1;
            if (rows[mid] < target) lo = mid + 1; else hi = mid;
        }
        rs[t] = lo;
    }
    __syncthreads();

    const int g   = lane >> 3;            // group -> local row
    const int sub = lane & 7;             // batch octet
    const int lj  = (w << 3) + g;
    const int s   = rs[lj];
    const int e   = rs[lj + 1];

    float acc[8];
    #pragma unroll
    for (int i = 0; i < 8; ++i) acc[i] = 0.f;

    for (int base = s; base < e; base += 4) {
        const int e1 = e - 1;
        const bool m1 = base + 1 < e, m2 = base + 2 < e, m3 = base + 3 < e;
        const int i1 = m1 ? base + 1 : e1;
        const int i2 = m2 ? base + 2 : e1;
        const int i3 = m3 ? base + 3 : e1;
        const int c0 = cols[base], c1 = cols[i1], c2 = cols[i2], c3 = cols[i3];
        const float v0 = vals[base];
        const float v1 = m1 ? vals[i1] : 0.f;
        const float v2 = m2 ? vals[i2] : 0.f;
        const float v3 = m3 ? vals[i3] : 0.f;
        const uint4 u0 = xh4[(size_t)c0 * 8 + sub];
        const uint4 u1 = xh4[(size_t)c1 * 8 + sub];
        const uint4 u2 = xh4[(size_t)c2 * 8 + sub];
        const uint4 u3 = xh4[(size_t)c3 * 8 + sub];
        float2 f;
        f = h2f(u0.x); acc[0] = fmaf(v0, f.x, acc[0]); acc[1] = fmaf(v0, f.y, acc[1]);
        f = h2f(u0.y); acc[2] = fmaf(v0, f.x, acc[2]); acc[3] = fmaf(v0, f.y, acc[3]);
        f = h2f(u0.z); acc[4] = fmaf(v0, f.x, acc[4]); acc[5] = fmaf(v0, f.y, acc[5]);
        f = h2f(u0.w); acc[6] = fmaf(v0, f.x, acc[6]); acc[7] = fmaf(v0, f.y, acc[7]);
        f = h2f(u1.x); acc[0] = fmaf(v1, f.x, acc[0]); acc[1] = fmaf(v1, f.y, acc[1]);
        f = h2f(u1.y); acc[2] = fmaf(v1, f.x, acc[2]); acc[3] = fmaf(v1, f.y, acc[3]);
        f = h2f(u1.z); acc[4] = fmaf(v1, f.x, acc[4]); acc[5] = fmaf(v1, f.y, acc[5]);
        f = h2f(u1.w); acc[6] = fmaf(v1, f.x, acc[6]); acc[7] = fmaf(v1, f.y, acc[7]);
        f = h2f(u2.x); acc[0] = fmaf(v2, f.x, acc[0]); acc[1] = fmaf(v2, f.y, acc[1]);
        f = h2f(u2.y); acc[2] = fmaf(v2, f.x, acc[2]); acc[3] = fmaf(v2, f.y, acc[3]);
        f = h2f(u2.z); acc[4] = fmaf(v2, f.x, acc[4]); acc[5] = fmaf(v2, f.y, acc[5]);
        f = h2f(u2.w); acc[6] = fmaf(v2, f.x, acc[6]); acc[7] = fmaf(v2, f.y, acc[7]);
        f = h2f(u3.x); acc[0] = fmaf(v3, f.x, acc[0]); acc[1] = fmaf(v3, f.y, acc[1]);
        f = h2f(u3.y); acc[2] = fmaf(v3, f.x, acc[2]); acc[3] = fmaf(v3, f.y, acc[3]);
        f = h2f(u3.z); acc[4] = fmaf(v3, f.x, acc[4]); acc[5] = fmaf(v3, f.y, acc[5]);
        f = h2f(u3.w); acc[6] = fmaf(v3, f.x, acc[6]); acc[7] = fmaf(v3, f.y, acc[7]);
    }

    // tile[lj][8sub+i]: bank = (lj + 8sub + i) mod 32 -> 2 lanes/bank = free
    #pragma unroll
    for (int i = 0; i < 8; ++i) tile[lj][(sub << 3) + i] = acc[i];
    __syncthreads();

    const int rc = r0 + lane;
    if (rc < OUT_F) {
        const float bv = bias[rc];
        for (int bb = w; bb < 64; bb += 8)
            out[(size_t)bb * OUT_F + rc] = tile[lane][bb] + bv;
    }
}

// ---------------------------------------------------------------------------
// Fallback (insufficient ws): gather from native x layout. Correct, slow.
// ---------------------------------------------------------------------------
__global__ __launch_bounds__(256) void k_spmm_fallback(
    const float* __restrict__ x,
    const float* __restrict__ vals,
    const int*   __restrict__ rows,
    const int*   __restrict__ cols,
    const float* __restrict__ bias,
    float* __restrict__ out) {
    __shared__ int   rstart[65];
    __shared__ float tile[64][65];
    const int r0   = blockIdx.x * 64;
    const int t    = threadIdx.x;
    const int lane = t & 63;
    const int w    = t >> 6;
    if (t < 65) {
        const int target = r0 + t;
        int lo = 0, hi = NNZ_N;
        while (lo < hi) {
            const int mid = (lo + hi) >> 1;
            if (rows[mid] < target) lo = mid + 1; else hi = mid;
        }
        rstart[t] = lo;
    }
    __syncthreads();
    for (int j = w; j < 64; j += 4) {
        const int s = rstart[j], e = rstart[j + 1];
        float acc = 0.f;
        const size_t base = (size_t)lane * IN_F;
        for (int idx = s; idx < e; ++idx)
            acc = fmaf(vals[idx], x[base + cols[idx]], acc);
        tile[j][lane] = acc;
    }
    __syncthreads();
    const int c = lane;
    if (r0 + c < OUT_F) {
        const float bv = bias[r0 + c];
        for (int bb = w; bb < 64; bb += 4)
            out[(size_t)bb * OUT_F + (r0 + c)] = tile[c][bb] + bv;
    }
}

extern "C" void kernel_launch(void* const* d_in, const int* in_sizes, int n_in,
                              void* d_out, int out_size, void* d_ws, size_t ws_size,
                              hipStream_t stream) {
    const float* x      = (const float*)d_in[0];
    const float* values = (const float*)d_in[1];
    const float* bias   = (const float*)d_in[2];
    const int*   rows   = (const int*)d_in[3];
    const int*   cols   = (const int*)d_in[4];
    float*       out    = (float*)d_out;

    const size_t need = (size_t)IN_F * 32 * sizeof(unsigned);   // xh: 12.8 MB

    if (ws_size >= need) {
        unsigned* xh = (unsigned*)d_ws;
        k_transpose<<<TBLK, 256, 0, stream>>>(x, xh);
        k_spmm<<<RBLK, 512, 0, stream>>>((const uint4*)xh, rows, cols, values, bias, out);
    } else {
        k_spmm_fallback<<<RBLK, 256, 0, stream>>>(x, values, rows, cols, bias, out);
    }
}